// Round 2
// baseline (1788.915 us; speedup 1.0000x reference)
//
#include <hip/hip_runtime.h>
#include <math.h>

#define DIMC 192
#define DIN 384
#define XZC 768
#define NPROJ 14
#define PSTR 16
#define LSEQ 9216
#define NBATCH 16
#define NTOK (NBATCH*LSEQ)     // 147456
#define CHUNK 256
#define NCH (LSEQ/CHUNK)       // 36

typedef unsigned short u16;
typedef unsigned int u32;
typedef __attribute__((ext_vector_type(8))) short bf16x8;
typedef __attribute__((ext_vector_type(4))) float f32x4;

__device__ __forceinline__ float bf2f(u16 a){
  union { u32 u; float f; } v; v.u = ((u32)a)<<16; return v.f;
}
__device__ __forceinline__ u16 f2bf(float f){
  union { u32 u; float f; } v; v.f = f;
  u32 r = v.u + 0x7FFFu + ((v.u>>16)&1u);
  return (u16)(r>>16);
}

// ---------------- weight conversion to bf16 ----------------
__global__ void k_convert(const float* __restrict__ Win, const float* __restrict__ Wout,
                          u16* __restrict__ WinB, u16* __restrict__ WoutB){
  int i = blockIdx.x*256 + threadIdx.x;
  if (i < DIMC*XZC)  WinB[i]  = f2bf(Win[i]);
  if (i < DIN*DIMC)  WoutB[i] = f2bf(Wout[i]);
}

// ---------------- fused LayerNorm + GEMM1: xz = LN(x) @ W_in ----------------
// 128 tokens per block, 256 threads (4 waves). A-tile (128x192 bf16) built once
// in LDS with in-kernel LN; then 12 passes of 64 output cols, BK=32 B staging.
// cols <384 -> xB, cols >=384 -> zB.
__global__ __launch_bounds__(256) void k_lngemm1(const float* __restrict__ x,
        const float* __restrict__ lnw, const float* __restrict__ lnb,
        const u16* __restrict__ Wb, u16* __restrict__ xB, u16* __restrict__ zB)
{
  __shared__ __align__(16) u16 As[128*200];  // stride 200 (400B, 16B-mult)
  __shared__ __align__(16) u16 Bs[64*40];    // transposed Bs[n][k], 32-k tile
  int tid = threadIdx.x, wv = tid>>6, lane = tid&63;
  int m0 = blockIdx.x * 128;
  // phase 1: LN of 32 rows per wave into As
  float w0=lnw[lane], w1=lnw[lane+64], w2=lnw[lane+128];
  float b0=lnb[lane], b1=lnb[lane+64], b2=lnb[lane+128];
  for (int i=0;i<32;++i){
    int row = wv*32 + i;
    const float* xp = x + (size_t)(m0+row)*DIMC;
    float v0=xp[lane], v1=xp[lane+64], v2=xp[lane+128];
    float s = v0+v1+v2;
    #pragma unroll
    for (int off=32; off; off>>=1) s += __shfl_xor(s, off);
    float mu = s * (1.0f/DIMC);
    float d0=v0-mu, d1=v1-mu, d2=v2-mu;
    float q = d0*d0+d1*d1+d2*d2;
    #pragma unroll
    for (int off=32; off; off>>=1) q += __shfl_xor(q, off);
    float rstd = rsqrtf(q*(1.0f/DIMC) + 1e-5f);
    u16* ap = As + row*200;
    ap[lane]     = f2bf(d0*rstd*w0 + b0);
    ap[lane+64]  = f2bf(d1*rstd*w1 + b1);
    ap[lane+128] = f2bf(d2*rstd*w2 + b2);
  }
  __syncthreads();
  int lr = lane&15, lq = lane>>4;
  for (int p=0; p<12; ++p){
    int n0 = p*64;
    f32x4 acc[2][4];
    #pragma unroll
    for (int i=0;i<2;++i)
      #pragma unroll
      for (int j=0;j<4;++j) acc[i][j] = (f32x4){0.f,0.f,0.f,0.f};
    for (int k0=0; k0<DIMC; k0+=32){
      __syncthreads();   // protect Bs from previous tile's readers
      {
        int n = tid & 63, kb = (tid>>6)<<3;
        union { u16 s[8]; uint4 v; } t;
        #pragma unroll
        for (int q_=0;q_<8;++q_) t.s[q_] = Wb[(size_t)(k0+kb+q_)*XZC + n0 + n];
        *(uint4*)(Bs + n*40 + kb) = t.v;
      }
      __syncthreads();
      bf16x8 af[2], bfrag[4];
      af[0] = *(const bf16x8*)(As + (wv*32 +      lr)*200 + k0 + lq*8);
      af[1] = *(const bf16x8*)(As + (wv*32 + 16 + lr)*200 + k0 + lq*8);
      #pragma unroll
      for (int j=0;j<4;++j) bfrag[j] = *(const bf16x8*)(Bs + (j*16+lr)*40 + lq*8);
      #pragma unroll
      for (int i=0;i<2;++i)
        #pragma unroll
        for (int j=0;j<4;++j)
          acc[i][j] = __builtin_amdgcn_mfma_f32_16x16x32_bf16(af[i], bfrag[j], acc[i][j], 0,0,0);
    }
    // epilogue: C/D layout col=lane&15, row=(lane>>4)*4+reg
    #pragma unroll
    for (int i=0;i<2;++i)
      #pragma unroll
      for (int j=0;j<4;++j)
        #pragma unroll
        for (int r=0;r<4;++r){
          int row = m0 + wv*32 + i*16 + lq*4 + r;
          int col = n0 + j*16 + lr;
          u16 v = f2bf(acc[i][j][r]);
          if (col < DIN) xB[(size_t)row*DIN + col] = v;
          else           zB[(size_t)row*DIN + (col-DIN)] = v;
        }
  }
}

// ---------------- conv3 + SiLU + x-proj reduction (proj only) ----------------
__global__ void k_conv(const u16* __restrict__ xB, const float* __restrict__ cw,
                       const float* __restrict__ cb, const float* __restrict__ Wx,
                       float* __restrict__ proj){
  int tok = blockIdx.x*4 + (threadIdx.x>>6);
  int lane = threadIdx.x & 63;
  int l = tok % LSEQ;
  float part[NPROJ];
  #pragma unroll
  for (int c=0;c<NPROJ;++c) part[c]=0.f;
  #pragma unroll
  for (int j=0;j<6;++j){
    int d = lane + j*64;
    float a = cb[d] + cw[d*3+2]*bf2f(xB[(size_t)tok*DIN + d]);
    if (l>=1) a += cw[d*3+1]*bf2f(xB[(size_t)(tok-1)*DIN + d]);
    if (l>=2) a += cw[d*3+0]*bf2f(xB[(size_t)(tok-2)*DIN + d]);
    float uu = a / (1.0f + expf(-a));
    const float* wrow = Wx + d*NPROJ;
    #pragma unroll
    for (int c=0;c<NPROJ;++c) part[c] += uu * wrow[c];
  }
  #pragma unroll
  for (int c=0;c<NPROJ;++c){
    float p = part[c];
    #pragma unroll
    for (int off=32; off; off>>=1) p += __shfl_xor(p, off);
    if (lane==0) proj[(size_t)tok*PSTR + c] = p;
  }
}

// ---------------- scan pass 1: per-chunk (P = prod dA, local h), u recomputed ----------------
__global__ __launch_bounds__(384) void k_scan1(const float* __restrict__ proj, const u16* __restrict__ xB,
    const float* __restrict__ cw, const float* __restrict__ cb,
    const float* __restrict__ Wdt, const float* __restrict__ bdt, const float* __restrict__ Alog,
    float* __restrict__ Pg, float* __restrict__ Hg){
  __shared__ float ps[CHUNK*NPROJ];
  int b = blockIdx.y, ch = blockIdx.x, d = threadIdx.x;
  int tok0 = b*LSEQ + ch*CHUNK;
  for (int idx = d; idx < CHUNK*NPROJ; idx += 384){
    int il = idx/NPROJ, c = idx - il*NPROJ;
    ps[idx] = proj[(size_t)(tok0+il)*PSTR + c];
  }
  __syncthreads();
  float wdt[12];
  #pragma unroll
  for (int r=0;r<12;++r) wdt[r] = Wdt[r*DIN+d];
  float bd = bdt[d];
  float Av = -expf(Alog[d]);
  float c0=cw[d*3], c1=cw[d*3+1], c2=cw[d*3+2], cbv=cb[d];
  float xm1=0.f, xm2=0.f;
  if (ch > 0){
    xm1 = bf2f(xB[(size_t)(tok0-1)*DIN + d]);
    xm2 = bf2f(xB[(size_t)(tok0-2)*DIN + d]);
  }
  float h = 0.f, P = 1.f;
  for (int il=0; il<CHUNK; ++il){
    float xc = bf2f(xB[(size_t)(tok0+il)*DIN + d]);
    float a = cbv + c2*xc + c1*xm1 + c0*xm2;
    float uu = a / (1.0f + expf(-a));
    const float* pr = ps + il*NPROJ;
    float xv = bd;
    #pragma unroll
    for (int r=0;r<12;++r) xv += pr[r]*wdt[r];
    float dt = fmaxf(xv,0.f) + log1pf(expf(-fabsf(xv)));   // softplus
    float dA = expf(dt*Av);
    h = dA*h + dt*pr[12]*uu;
    P *= dA;
    xm2 = xm1; xm1 = xc;
  }
  int o = (b*NCH + ch)*DIN + d;
  Pg[o] = P; Hg[o] = h;
}

// ---------------- scan pass 2: sequential carry combine over chunks ----------------
__global__ void k_scan2(const float* __restrict__ Pg, const float* __restrict__ Hg,
                        float* __restrict__ hin){
  int idx = blockIdx.x*256 + threadIdx.x;   // 0..6143 = b*384+d
  int b = idx/DIN, d = idx - b*DIN;
  float run = 0.f;
  for (int ch=0; ch<NCH; ++ch){
    int o = (b*NCH+ch)*DIN + d;
    hin[o] = run;
    run = Pg[o]*run + Hg[o];
  }
}

// ---------------- scan pass 3: re-scan with carry, y = (h*C + u*D)*silu(z) in-place over zB ----------------
__global__ __launch_bounds__(384) void k_scan3(const float* __restrict__ proj, const u16* __restrict__ xB,
    const float* __restrict__ cw, const float* __restrict__ cb,
    const float* __restrict__ Wdt, const float* __restrict__ bdt,
    const float* __restrict__ Alog, const float* __restrict__ Dp,
    const float* __restrict__ hin, u16* __restrict__ zB){
  __shared__ float ps[CHUNK*NPROJ];
  int b = blockIdx.y, ch = blockIdx.x, d = threadIdx.x;
  int tok0 = b*LSEQ + ch*CHUNK;
  for (int idx = d; idx < CHUNK*NPROJ; idx += 384){
    int il = idx/NPROJ, c = idx - il*NPROJ;
    ps[idx] = proj[(size_t)(tok0+il)*PSTR + c];
  }
  __syncthreads();
  float wdt[12];
  #pragma unroll
  for (int r=0;r<12;++r) wdt[r] = Wdt[r*DIN+d];
  float bd = bdt[d];
  float Av = -expf(Alog[d]);
  float Dv = Dp[d];
  float c0=cw[d*3], c1=cw[d*3+1], c2=cw[d*3+2], cbv=cb[d];
  float xm1=0.f, xm2=0.f;
  if (ch > 0){
    xm1 = bf2f(xB[(size_t)(tok0-1)*DIN + d]);
    xm2 = bf2f(xB[(size_t)(tok0-2)*DIN + d]);
  }
  float h = hin[(b*NCH+ch)*DIN + d];
  for (int il=0; il<CHUNK; ++il){
    float xc = bf2f(xB[(size_t)(tok0+il)*DIN + d]);
    float a = cbv + c2*xc + c1*xm1 + c0*xm2;
    float uu = a / (1.0f + expf(-a));
    const float* pr = ps + il*NPROJ;
    float xv = bd;
    #pragma unroll
    for (int r=0;r<12;++r) xv += pr[r]*wdt[r];
    float dt = fmaxf(xv,0.f) + log1pf(expf(-fabsf(xv)));
    float dA = expf(dt*Av);
    h = dA*h + dt*pr[12]*uu;
    size_t zo = (size_t)(tok0+il)*DIN + d;
    float zz = bf2f(zB[zo]);
    float sz = zz / (1.0f + expf(-zz));
    zB[zo] = f2bf((h*pr[13] + uu*Dv)*sz);   // in-place: same thread, same slot
    xm2 = xm1; xm1 = xc;
  }
}

// ---------------- GEMM2: out = y @ W_out + x (residual), y = zB in-place ----------------
__global__ __launch_bounds__(256) void k_gemm2(const u16* __restrict__ A, const u16* __restrict__ B,
        const float* __restrict__ R, float* __restrict__ C)
{
  __shared__ __align__(16) u16 As[128*40];
  __shared__ __align__(16) u16 Bs[64*40];
  int tid = threadIdx.x;
  int m0 = blockIdx.x * 128;
  int n0 = blockIdx.y * 64;
  int wv = tid>>6, lane = tid&63;
  int lr = lane&15, lq = lane>>4;
  f32x4 acc[2][4];
  #pragma unroll
  for (int i=0;i<2;++i)
    #pragma unroll
    for (int j=0;j<4;++j) acc[i][j] = (f32x4){0.f,0.f,0.f,0.f};

  for (int k0=0; k0<DIN; k0+=32){
    #pragma unroll
    for (int it=0; it<2; ++it){
      int c = tid + 256*it;
      int row = c>>2, kc = (c&3)<<3;
      uint4 v = *(const uint4*)(A + (size_t)(m0+row)*DIN + k0 + kc);
      *(uint4*)(As + row*40 + kc) = v;
    }
    {
      int n = tid & 63, kb = (tid>>6)<<3;
      union { u16 s[8]; uint4 v; } tmp;
      #pragma unroll
      for (int j=0;j<8;++j) tmp.s[j] = B[(size_t)(k0+kb+j)*DIMC + n0 + n];
      *(uint4*)(Bs + n*40 + kb) = tmp.v;
    }
    __syncthreads();
    bf16x8 af[2], bfrag[4];
    af[0] = *(const bf16x8*)(As + (wv*32 +      lr)*40 + lq*8);
    af[1] = *(const bf16x8*)(As + (wv*32 + 16 + lr)*40 + lq*8);
    #pragma unroll
    for (int j=0;j<4;++j) bfrag[j] = *(const bf16x8*)(Bs + (j*16+lr)*40 + lq*8);
    #pragma unroll
    for (int i=0;i<2;++i)
      #pragma unroll
      for (int j=0;j<4;++j)
        acc[i][j] = __builtin_amdgcn_mfma_f32_16x16x32_bf16(af[i], bfrag[j], acc[i][j], 0,0,0);
    __syncthreads();
  }
  #pragma unroll
  for (int i=0;i<2;++i)
    #pragma unroll
    for (int j=0;j<4;++j)
      #pragma unroll
      for (int r=0;r<4;++r){
        int row = m0 + wv*32 + i*16 + lq*4 + r;
        int col = n0 + j*16 + lr;
        size_t o = (size_t)row*DIMC + col;
        C[o] = acc[i][j][r] + R[o];
      }
}

// ---------------- launch ----------------
extern "C" void kernel_launch(void* const* d_in, const int* in_sizes, int n_in,
                              void* d_out, int out_size, void* d_ws, size_t ws_size,
                              hipStream_t stream) {
  const float* x     = (const float*)d_in[0];
  const float* lnw   = (const float*)d_in[1];
  const float* lnb   = (const float*)d_in[2];
  const float* Win   = (const float*)d_in[3];
  const float* convw = (const float*)d_in[4];
  const float* convb = (const float*)d_in[5];
  const float* Wx    = (const float*)d_in[6];
  const float* Wdt   = (const float*)d_in[7];
  const float* bdt   = (const float*)d_in[8];
  const float* Alog  = (const float*)d_in[9];
  const float* Dp    = (const float*)d_in[10];
  const float* Wout  = (const float*)d_in[11];
  float* out = (float*)d_out;

  char* ws = (char*)d_ws;
  size_t off = 0;
  auto alloc = [&](size_t bytes){ size_t r = off; off += (bytes + 255) & ~(size_t)255; return r; };
  u16*   xB    = (u16*)  (ws + alloc((size_t)NTOK*DIN*2));    // 113.2 MB
  u16*   zB    = (u16*)  (ws + alloc((size_t)NTOK*DIN*2));    // 113.2 MB (y in-place later)
  float* proj  = (float*)(ws + alloc((size_t)NTOK*PSTR*4));   //   9.4 MB
  u16*   WinB  = (u16*)  (ws + alloc((size_t)DIMC*XZC*2));
  u16*   WoutB = (u16*)  (ws + alloc((size_t)DIN*DIMC*2));
  float* Pg    = (float*)(ws + alloc((size_t)NBATCH*NCH*DIN*4));
  float* Hg    = (float*)(ws + alloc((size_t)NBATCH*NCH*DIN*4));
  float* hin   = (float*)(ws + alloc((size_t)NBATCH*NCH*DIN*4));
  // total ≈ 239 MB

  k_convert<<<576, 256, 0, stream>>>(Win, Wout, WinB, WoutB);
  k_lngemm1<<<NTOK/128, 256, 0, stream>>>(x, lnw, lnb, WinB, xB, zB);
  k_conv<<<NTOK/4, 256, 0, stream>>>(xB, convw, convb, Wx, proj);
  {
    dim3 g(NCH, NBATCH);
    k_scan1<<<g, 384, 0, stream>>>(proj, xB, convw, convb, Wdt, bdt, Alog, Pg, Hg);
  }
  k_scan2<<<24, 256, 0, stream>>>(Pg, Hg, hin);
  {
    dim3 g(NCH, NBATCH);
    k_scan3<<<g, 384, 0, stream>>>(proj, xB, convw, convb, Wdt, bdt, Alog, Dp, hin, zB);
  }
  {
    dim3 g(NTOK/128, DIMC/64);
    k_gemm2<<<g, 256, 0, stream>>>(zB, WoutB, x, out);
  }
}

// Round 3
// 1066.829 us; speedup vs baseline: 1.6769x; 1.6769x over previous
//
#include <hip/hip_runtime.h>
#include <math.h>

#define DIMC 192
#define DIN 384
#define XZC 768
#define NPROJ 14
#define PSTR 16
#define LSEQ 9216
#define NBATCH 16
#define NTOK (NBATCH*LSEQ)     // 147456
#define CHUNK 128
#define NCH (LSEQ/CHUNK)       // 72

typedef unsigned short u16;
typedef unsigned int u32;
typedef __attribute__((ext_vector_type(8))) short bf16x8;
typedef __attribute__((ext_vector_type(4))) float f32x4;

__device__ __forceinline__ float bf2f(u16 a){
  union { u32 u; float f; } v; v.u = ((u32)a)<<16; return v.f;
}
__device__ __forceinline__ u16 f2bf(float f){
  union { u32 u; float f; } v; v.f = f;
  u32 r = v.u + 0x7FFFu + ((v.u>>16)&1u);
  return (u16)(r>>16);
}
__device__ __forceinline__ float frcp(float x){ return __builtin_amdgcn_rcpf(x); }
// native softplus: ~8 instrs vs libm's ~100+
__device__ __forceinline__ float softplus_f(float x){
  return fmaxf(x, 0.f) + __logf(1.f + __expf(-fabsf(x)));
}
__device__ __forceinline__ float silu_f(float a){
  return a * frcp(1.f + __expf(-a));
}

// ---------------- weight conversion to bf16 ----------------
__global__ void k_convert(const float* __restrict__ Win, const float* __restrict__ Wout,
                          u16* __restrict__ WinB, u16* __restrict__ WoutB){
  int i = blockIdx.x*256 + threadIdx.x;
  if (i < DIMC*XZC)  WinB[i]  = f2bf(Win[i]);
  if (i < DIN*DIMC)  WoutB[i] = f2bf(Wout[i]);
}

// ---------------- fused LayerNorm + GEMM1: xz = LN(x) @ W_in ----------------
__global__ __launch_bounds__(256) void k_lngemm1(const float* __restrict__ x,
        const float* __restrict__ lnw, const float* __restrict__ lnb,
        const u16* __restrict__ Wb, u16* __restrict__ xB, u16* __restrict__ zB)
{
  __shared__ __align__(16) u16 As[128*200];
  __shared__ __align__(16) u16 Bs[64*40];
  int tid = threadIdx.x, wv = tid>>6, lane = tid&63;
  int m0 = blockIdx.x * 128;
  float w0=lnw[lane], w1=lnw[lane+64], w2=lnw[lane+128];
  float b0=lnb[lane], b1=lnb[lane+64], b2=lnb[lane+128];
  for (int i=0;i<32;++i){
    int row = wv*32 + i;
    const float* xp = x + (size_t)(m0+row)*DIMC;
    float v0=xp[lane], v1=xp[lane+64], v2=xp[lane+128];
    float s = v0+v1+v2;
    #pragma unroll
    for (int off=32; off; off>>=1) s += __shfl_xor(s, off);
    float mu = s * (1.0f/DIMC);
    float d0=v0-mu, d1=v1-mu, d2=v2-mu;
    float q = d0*d0+d1*d1+d2*d2;
    #pragma unroll
    for (int off=32; off; off>>=1) q += __shfl_xor(q, off);
    float rstd = rsqrtf(q*(1.0f/DIMC) + 1e-5f);
    u16* ap = As + row*200;
    ap[lane]     = f2bf(d0*rstd*w0 + b0);
    ap[lane+64]  = f2bf(d1*rstd*w1 + b1);
    ap[lane+128] = f2bf(d2*rstd*w2 + b2);
  }
  __syncthreads();
  int lr = lane&15, lq = lane>>4;
  for (int p=0; p<12; ++p){
    int n0 = p*64;
    f32x4 acc[2][4];
    #pragma unroll
    for (int i=0;i<2;++i)
      #pragma unroll
      for (int j=0;j<4;++j) acc[i][j] = (f32x4){0.f,0.f,0.f,0.f};
    for (int k0=0; k0<DIMC; k0+=32){
      __syncthreads();
      {
        int n = tid & 63, kb = (tid>>6)<<3;
        union { u16 s[8]; uint4 v; } t;
        #pragma unroll
        for (int q_=0;q_<8;++q_) t.s[q_] = Wb[(size_t)(k0+kb+q_)*XZC + n0 + n];
        *(uint4*)(Bs + n*40 + kb) = t.v;
      }
      __syncthreads();
      bf16x8 af[2], bfrag[4];
      af[0] = *(const bf16x8*)(As + (wv*32 +      lr)*200 + k0 + lq*8);
      af[1] = *(const bf16x8*)(As + (wv*32 + 16 + lr)*200 + k0 + lq*8);
      #pragma unroll
      for (int j=0;j<4;++j) bfrag[j] = *(const bf16x8*)(Bs + (j*16+lr)*40 + lq*8);
      #pragma unroll
      for (int i=0;i<2;++i)
        #pragma unroll
        for (int j=0;j<4;++j)
          acc[i][j] = __builtin_amdgcn_mfma_f32_16x16x32_bf16(af[i], bfrag[j], acc[i][j], 0,0,0);
    }
    #pragma unroll
    for (int i=0;i<2;++i)
      #pragma unroll
      for (int j=0;j<4;++j)
        #pragma unroll
        for (int r=0;r<4;++r){
          int row = m0 + wv*32 + i*16 + lq*4 + r;
          int col = n0 + j*16 + lr;
          u16 v = f2bf(acc[i][j][r]);
          if (col < DIN) xB[(size_t)row*DIN + col] = v;
          else           zB[(size_t)row*DIN + (col-DIN)] = v;
        }
  }
}

// ---------------- conv3 + SiLU + x-proj reduction (proj only) ----------------
__global__ void k_conv(const u16* __restrict__ xB, const float* __restrict__ cw,
                       const float* __restrict__ cb, const float* __restrict__ Wx,
                       float* __restrict__ proj){
  int tok = blockIdx.x*4 + (threadIdx.x>>6);
  int lane = threadIdx.x & 63;
  int l = tok % LSEQ;
  float part[NPROJ];
  #pragma unroll
  for (int c=0;c<NPROJ;++c) part[c]=0.f;
  #pragma unroll
  for (int j=0;j<6;++j){
    int d = lane + j*64;
    float a = cb[d] + cw[d*3+2]*bf2f(xB[(size_t)tok*DIN + d]);
    if (l>=1) a += cw[d*3+1]*bf2f(xB[(size_t)(tok-1)*DIN + d]);
    if (l>=2) a += cw[d*3+0]*bf2f(xB[(size_t)(tok-2)*DIN + d]);
    float uu = silu_f(a);
    const float* wrow = Wx + d*NPROJ;
    #pragma unroll
    for (int c=0;c<NPROJ;++c) part[c] += uu * wrow[c];
  }
  #pragma unroll
  for (int c=0;c<NPROJ;++c){
    float p = part[c];
    #pragma unroll
    for (int off=32; off; off>>=1) p += __shfl_xor(p, off);
    if (lane==0) proj[(size_t)tok*PSTR + c] = p;
  }
}

// ---------------- scan pass 1: per-chunk (P = prod dA, local h) ----------------
__global__ __launch_bounds__(384) void k_scan1(const float* __restrict__ proj, const u16* __restrict__ xB,
    const float* __restrict__ cw, const float* __restrict__ cb,
    const float* __restrict__ Wdt, const float* __restrict__ bdt, const float* __restrict__ Alog,
    float* __restrict__ Pg, float* __restrict__ Hg){
  __shared__ __align__(16) float ps[CHUNK*PSTR];
  int b = blockIdx.y, ch = blockIdx.x, d = threadIdx.x;
  int tok0 = b*LSEQ + ch*CHUNK;
  {
    const float4* src = (const float4*)(proj + (size_t)tok0*PSTR);
    float4* dst = (float4*)ps;
    for (int i = d; i < CHUNK*PSTR/4; i += 384) dst[i] = src[i];
  }
  __syncthreads();
  float wdt[12];
  #pragma unroll
  for (int r=0;r<12;++r) wdt[r] = Wdt[r*DIN+d];
  float bd = bdt[d];
  float Av = -__expf(Alog[d]);
  float c0=cw[d*3], c1=cw[d*3+1], c2=cw[d*3+2], cbv=cb[d];
  float xm1=0.f, xm2=0.f;
  if (ch > 0){
    xm1 = bf2f(xB[(size_t)(tok0-1)*DIN + d]);
    xm2 = bf2f(xB[(size_t)(tok0-2)*DIN + d]);
  }
  float h = 0.f, P = 1.f;
  #pragma unroll 4
  for (int il=0; il<CHUNK; ++il){
    float xc = bf2f(xB[(size_t)(tok0+il)*DIN + d]);
    const float4* pq = (const float4*)(ps + il*PSTR);
    float4 q0=pq[0], q1=pq[1], q2=pq[2], q3=pq[3];
    float a = cbv + c2*xc + c1*xm1 + c0*xm2;
    float uu = silu_f(a);
    float xv = bd + q0.x*wdt[0]+q0.y*wdt[1]+q0.z*wdt[2]+q0.w*wdt[3]
                  + q1.x*wdt[4]+q1.y*wdt[5]+q1.z*wdt[6]+q1.w*wdt[7]
                  + q2.x*wdt[8]+q2.y*wdt[9]+q2.z*wdt[10]+q2.w*wdt[11];
    float dt = softplus_f(xv);
    float dA = __expf(dt*Av);
    h = dA*h + dt*q3.x*uu;
    P *= dA;
    xm2 = xm1; xm1 = xc;
  }
  int o = (b*NCH + ch)*DIN + d;
  Pg[o] = P; Hg[o] = h;
}

// ---------------- scan pass 2: sequential carry combine over chunks ----------------
__global__ void k_scan2(const float* __restrict__ Pg, const float* __restrict__ Hg,
                        float* __restrict__ hin){
  int idx = blockIdx.x*256 + threadIdx.x;   // 0..6143 = b*384+d
  int b = idx/DIN, d = idx - b*DIN;
  float run = 0.f;
  #pragma unroll 4
  for (int ch=0; ch<NCH; ++ch){
    int o = (b*NCH+ch)*DIN + d;
    hin[o] = run;
    run = Pg[o]*run + Hg[o];
  }
}

// ---------------- scan pass 3: re-scan with carry, y in-place over zB ----------------
__global__ __launch_bounds__(384) void k_scan3(const float* __restrict__ proj, const u16* __restrict__ xB,
    const float* __restrict__ cw, const float* __restrict__ cb,
    const float* __restrict__ Wdt, const float* __restrict__ bdt,
    const float* __restrict__ Alog, const float* __restrict__ Dp,
    const float* __restrict__ hin, u16* __restrict__ zB){
  __shared__ __align__(16) float ps[CHUNK*PSTR];
  int b = blockIdx.y, ch = blockIdx.x, d = threadIdx.x;
  int tok0 = b*LSEQ + ch*CHUNK;
  {
    const float4* src = (const float4*)(proj + (size_t)tok0*PSTR);
    float4* dst = (float4*)ps;
    for (int i = d; i < CHUNK*PSTR/4; i += 384) dst[i] = src[i];
  }
  __syncthreads();
  float wdt[12];
  #pragma unroll
  for (int r=0;r<12;++r) wdt[r] = Wdt[r*DIN+d];
  float bd = bdt[d];
  float Av = -__expf(Alog[d]);
  float Dv = Dp[d];
  float c0=cw[d*3], c1=cw[d*3+1], c2=cw[d*3+2], cbv=cb[d];
  float xm1=0.f, xm2=0.f;
  if (ch > 0){
    xm1 = bf2f(xB[(size_t)(tok0-1)*DIN + d]);
    xm2 = bf2f(xB[(size_t)(tok0-2)*DIN + d]);
  }
  float h = hin[(b*NCH+ch)*DIN + d];
  #pragma unroll 4
  for (int il=0; il<CHUNK; ++il){
    float xc = bf2f(xB[(size_t)(tok0+il)*DIN + d]);
    const float4* pq = (const float4*)(ps + il*PSTR);
    float4 q0=pq[0], q1=pq[1], q2=pq[2], q3=pq[3];
    float a = cbv + c2*xc + c1*xm1 + c0*xm2;
    float uu = silu_f(a);
    float xv = bd + q0.x*wdt[0]+q0.y*wdt[1]+q0.z*wdt[2]+q0.w*wdt[3]
                  + q1.x*wdt[4]+q1.y*wdt[5]+q1.z*wdt[6]+q1.w*wdt[7]
                  + q2.x*wdt[8]+q2.y*wdt[9]+q2.z*wdt[10]+q2.w*wdt[11];
    float dt = softplus_f(xv);
    float dA = __expf(dt*Av);
    h = dA*h + dt*q3.x*uu;
    size_t zo = (size_t)(tok0+il)*DIN + d;
    float zz = bf2f(zB[zo]);
    zB[zo] = f2bf((h*q3.y + uu*Dv)*silu_f(zz));
    xm2 = xm1; xm1 = xc;
  }
}

// ---------------- GEMM2: out = y @ W_out + x ----------------
__global__ __launch_bounds__(256) void k_gemm2(const u16* __restrict__ A, const u16* __restrict__ B,
        const float* __restrict__ R, float* __restrict__ C)
{
  __shared__ __align__(16) u16 As[128*40];
  __shared__ __align__(16) u16 Bs[64*40];
  int tid = threadIdx.x;
  int m0 = blockIdx.x * 128;
  int n0 = blockIdx.y * 64;
  int wv = tid>>6, lane = tid&63;
  int lr = lane&15, lq = lane>>4;
  f32x4 acc[2][4];
  #pragma unroll
  for (int i=0;i<2;++i)
    #pragma unroll
    for (int j=0;j<4;++j) acc[i][j] = (f32x4){0.f,0.f,0.f,0.f};

  for (int k0=0; k0<DIN; k0+=32){
    #pragma unroll
    for (int it=0; it<2; ++it){
      int c = tid + 256*it;
      int row = c>>2, kc = (c&3)<<3;
      uint4 v = *(const uint4*)(A + (size_t)(m0+row)*DIN + k0 + kc);
      *(uint4*)(As + row*40 + kc) = v;
    }
    {
      int n = tid & 63, kb = (tid>>6)<<3;
      union { u16 s[8]; uint4 v; } tmp;
      #pragma unroll
      for (int j=0;j<8;++j) tmp.s[j] = B[(size_t)(k0+kb+j)*DIMC + n0 + n];
      *(uint4*)(Bs + n*40 + kb) = tmp.v;
    }
    __syncthreads();
    bf16x8 af[2], bfrag[4];
    af[0] = *(const bf16x8*)(As + (wv*32 +      lr)*40 + lq*8);
    af[1] = *(const bf16x8*)(As + (wv*32 + 16 + lr)*40 + lq*8);
    #pragma unroll
    for (int j=0;j<4;++j) bfrag[j] = *(const bf16x8*)(Bs + (j*16+lr)*40 + lq*8);
    #pragma unroll
    for (int i=0;i<2;++i)
      #pragma unroll
      for (int j=0;j<4;++j)
        acc[i][j] = __builtin_amdgcn_mfma_f32_16x16x32_bf16(af[i], bfrag[j], acc[i][j], 0,0,0);
    __syncthreads();
  }
  #pragma unroll
  for (int i=0;i<2;++i)
    #pragma unroll
    for (int j=0;j<4;++j)
      #pragma unroll
      for (int r=0;r<4;++r){
        int row = m0 + wv*32 + i*16 + lq*4 + r;
        int col = n0 + j*16 + lr;
        size_t o = (size_t)row*DIMC + col;
        C[o] = acc[i][j][r] + R[o];
      }
}

// ---------------- launch ----------------
extern "C" void kernel_launch(void* const* d_in, const int* in_sizes, int n_in,
                              void* d_out, int out_size, void* d_ws, size_t ws_size,
                              hipStream_t stream) {
  const float* x     = (const float*)d_in[0];
  const float* lnw   = (const float*)d_in[1];
  const float* lnb   = (const float*)d_in[2];
  const float* Win   = (const float*)d_in[3];
  const float* convw = (const float*)d_in[4];
  const float* convb = (const float*)d_in[5];
  const float* Wx    = (const float*)d_in[6];
  const float* Wdt   = (const float*)d_in[7];
  const float* bdt   = (const float*)d_in[8];
  const float* Alog  = (const float*)d_in[9];
  const float* Dp    = (const float*)d_in[10];
  const float* Wout  = (const float*)d_in[11];
  float* out = (float*)d_out;

  char* ws = (char*)d_ws;
  size_t off = 0;
  auto alloc = [&](size_t bytes){ size_t r = off; off += (bytes + 255) & ~(size_t)255; return r; };
  u16*   xB    = (u16*)  (ws + alloc((size_t)NTOK*DIN*2));
  u16*   zB    = (u16*)  (ws + alloc((size_t)NTOK*DIN*2));
  float* proj  = (float*)(ws + alloc((size_t)NTOK*PSTR*4));
  u16*   WinB  = (u16*)  (ws + alloc((size_t)DIMC*XZC*2));
  u16*   WoutB = (u16*)  (ws + alloc((size_t)DIN*DIMC*2));
  float* Pg    = (float*)(ws + alloc((size_t)NBATCH*NCH*DIN*4));
  float* Hg    = (float*)(ws + alloc((size_t)NBATCH*NCH*DIN*4));
  float* hin   = (float*)(ws + alloc((size_t)NBATCH*NCH*DIN*4));
  // total ≈ 231 MB

  k_convert<<<576, 256, 0, stream>>>(Win, Wout, WinB, WoutB);
  k_lngemm1<<<NTOK/128, 256, 0, stream>>>(x, lnw, lnb, WinB, xB, zB);
  k_conv<<<NTOK/4, 256, 0, stream>>>(xB, convw, convb, Wx, proj);
  {
    dim3 g(NCH, NBATCH);
    k_scan1<<<g, 384, 0, stream>>>(proj, xB, convw, convb, Wdt, bdt, Alog, Pg, Hg);
  }
  k_scan2<<<24, 256, 0, stream>>>(Pg, Hg, hin);
  {
    dim3 g(NCH, NBATCH);
    k_scan3<<<g, 384, 0, stream>>>(proj, xB, convw, convb, Wdt, bdt, Alog, Dp, hin, zB);
  }
  {
    dim3 g(NTOK/128, DIMC/64);
    k_gemm2<<<g, 256, 0, stream>>>(zB, WoutB, x, out);
  }
}

// Round 4
// 828.653 us; speedup vs baseline: 2.1588x; 1.2874x over previous
//
#include <hip/hip_runtime.h>
#include <math.h>

#define DIMC 192
#define DIN 384
#define XZC 768
#define NPROJ 14
#define PSTR 16
#define LSEQ 9216
#define NBATCH 16
#define NTOK (NBATCH*LSEQ)     // 147456
#define CHUNK 128
#define NCH (LSEQ/CHUNK)       // 72

typedef unsigned short u16;
typedef unsigned int u32;
typedef __attribute__((ext_vector_type(8))) short bf16x8;
typedef __attribute__((ext_vector_type(4))) float f32x4;

__device__ __forceinline__ float bf2f(u16 a){
  union { u32 u; float f; } v; v.u = ((u32)a)<<16; return v.f;
}
__device__ __forceinline__ u16 f2bf(float f){
  union { u32 u; float f; } v; v.f = f;
  u32 r = v.u + 0x7FFFu + ((v.u>>16)&1u);
  return (u16)(r>>16);
}
__device__ __forceinline__ float frcp(float x){ return __builtin_amdgcn_rcpf(x); }
__device__ __forceinline__ float softplus_f(float x){
  return fmaxf(x, 0.f) + __logf(1.f + __expf(-fabsf(x)));
}
__device__ __forceinline__ float silu_f(float a){
  return a * frcp(1.f + __expf(-a));
}

// ---------------- weight conversion / packing ----------------
// WinB, WoutB: bf16 copies. Wxp: B-fragment-packed Wx (K=384, N=16 zero-pad),
// layout [(kstep*4+quad)*16+n)*8+j] so a lane's 8 B-frag elems are contiguous.
// cwT[tap][384]: transposed conv weights (float).
__global__ void k_convert(const float* __restrict__ Win, const float* __restrict__ Wout,
                          const float* __restrict__ Wx, const float* __restrict__ cw,
                          u16* __restrict__ WinB, u16* __restrict__ WoutB,
                          u16* __restrict__ Wxp, float* __restrict__ cwT){
  int i = blockIdx.x*256 + threadIdx.x;
  if (i < DIMC*XZC)  WinB[i]  = f2bf(Win[i]);
  if (i < DIN*DIMC)  WoutB[i] = f2bf(Wout[i]);
  if (i < 12*4*16*8){
    int j = i&7, n = (i>>3)&15, quad = (i>>7)&3, kstep = i>>9;
    int k = kstep*32 + quad*8 + j;
    Wxp[i] = (n < NPROJ) ? f2bf(Wx[k*NPROJ + n]) : (u16)0;
  }
  if (i < 3*DIN){
    int tap = i / DIN, ch = i - tap*DIN;
    cwT[i] = cw[ch*3 + tap];
  }
}

// ---------------- fused LayerNorm + GEMM1: xz = LN(x) @ W_in ----------------
__global__ __launch_bounds__(256) void k_lngemm1(const float* __restrict__ x,
        const float* __restrict__ lnw, const float* __restrict__ lnb,
        const u16* __restrict__ Wb, u16* __restrict__ xB, u16* __restrict__ zB)
{
  __shared__ __align__(16) u16 As[128*200];
  __shared__ __align__(16) u16 Bs[64*40];
  int tid = threadIdx.x, wv = tid>>6, lane = tid&63;
  int m0 = blockIdx.x * 128;
  float w0=lnw[lane], w1=lnw[lane+64], w2=lnw[lane+128];
  float b0=lnb[lane], b1=lnb[lane+64], b2=lnb[lane+128];
  for (int i=0;i<32;++i){
    int row = wv*32 + i;
    const float* xp = x + (size_t)(m0+row)*DIMC;
    float v0=xp[lane], v1=xp[lane+64], v2=xp[lane+128];
    float s = v0+v1+v2;
    #pragma unroll
    for (int off=32; off; off>>=1) s += __shfl_xor(s, off);
    float mu = s * (1.0f/DIMC);
    float d0=v0-mu, d1=v1-mu, d2=v2-mu;
    float q = d0*d0+d1*d1+d2*d2;
    #pragma unroll
    for (int off=32; off; off>>=1) q += __shfl_xor(q, off);
    float rstd = rsqrtf(q*(1.0f/DIMC) + 1e-5f);
    u16* ap = As + row*200;
    ap[lane]     = f2bf(d0*rstd*w0 + b0);
    ap[lane+64]  = f2bf(d1*rstd*w1 + b1);
    ap[lane+128] = f2bf(d2*rstd*w2 + b2);
  }
  __syncthreads();
  int lr = lane&15, lq = lane>>4;
  for (int p=0; p<12; ++p){
    int n0 = p*64;
    f32x4 acc[2][4];
    #pragma unroll
    for (int i=0;i<2;++i)
      #pragma unroll
      for (int j=0;j<4;++j) acc[i][j] = (f32x4){0.f,0.f,0.f,0.f};
    for (int k0=0; k0<DIMC; k0+=32){
      __syncthreads();
      {
        int n = tid & 63, kb = (tid>>6)<<3;
        union { u16 s[8]; uint4 v; } t;
        #pragma unroll
        for (int q_=0;q_<8;++q_) t.s[q_] = Wb[(size_t)(k0+kb+q_)*XZC + n0 + n];
        *(uint4*)(Bs + n*40 + kb) = t.v;
      }
      __syncthreads();
      bf16x8 af[2], bfrag[4];
      af[0] = *(const bf16x8*)(As + (wv*32 +      lr)*200 + k0 + lq*8);
      af[1] = *(const bf16x8*)(As + (wv*32 + 16 + lr)*200 + k0 + lq*8);
      #pragma unroll
      for (int j=0;j<4;++j) bfrag[j] = *(const bf16x8*)(Bs + (j*16+lr)*40 + lq*8);
      #pragma unroll
      for (int i=0;i<2;++i)
        #pragma unroll
        for (int j=0;j<4;++j)
          acc[i][j] = __builtin_amdgcn_mfma_f32_16x16x32_bf16(af[i], bfrag[j], acc[i][j], 0,0,0);
    }
    #pragma unroll
    for (int i=0;i<2;++i)
      #pragma unroll
      for (int j=0;j<4;++j)
        #pragma unroll
        for (int r=0;r<4;++r){
          int row = m0 + wv*32 + i*16 + lq*4 + r;
          int col = n0 + j*16 + lr;
          u16 v = f2bf(acc[i][j][r]);
          if (col < DIN) xB[(size_t)row*DIN + col] = v;
          else           zB[(size_t)row*DIN + (col-DIN)] = v;
        }
  }
}

// ---------------- conv3 + SiLU + MFMA projection: proj = silu(conv(xB)) @ Wx ----------------
// wave = 16 tokens (M=16), N=16 (14 + 2 pad), K=384 over 12 MFMA steps.
// Lane computes u for token (tok0+lane&15), 8 consecutive channels per step,
// fragment built in registers; no LDS, no shuffles.
__global__ __launch_bounds__(256) void k_conv(const u16* __restrict__ xB,
        const float* __restrict__ cwT, const float* __restrict__ cb,
        const u16* __restrict__ Wxp, float* __restrict__ proj){
  int tid = threadIdx.x, wv = tid>>6, lane = tid&63;
  int lr = lane&15, lq = lane>>4;
  int tok0 = blockIdx.x*64 + wv*16;
  int token = tok0 + lr;
  int l = token % LSEQ;
  float m1 = (l>=1)?1.f:0.f, m2 = (l>=2)?1.f:0.f;
  int tm1 = (l>=1)? token-1 : token;   // clamped: no OOB, value masked
  int tm2 = (l>=2)? token-2 : token;
  bf16x8 bfrag[12];
  #pragma unroll
  for (int ks=0;ks<12;++ks)
    bfrag[ks] = *(const bf16x8*)(Wxp + (size_t)ks*512 + (size_t)lane*8);
  f32x4 acc = (f32x4){0.f,0.f,0.f,0.f};
  #pragma unroll
  for (int ks=0;ks<12;++ks){
    int ch0 = ks*32 + lq*8;
    bf16x8 x0 = *(const bf16x8*)(xB + (size_t)token*DIN + ch0);
    bf16x8 x1 = *(const bf16x8*)(xB + (size_t)tm1*DIN + ch0);
    bf16x8 x2 = *(const bf16x8*)(xB + (size_t)tm2*DIN + ch0);
    const float* w2 = cwT + 2*DIN + ch0;
    const float* w1 = cwT + 1*DIN + ch0;
    const float* w0 = cwT + 0*DIN + ch0;
    const float* cbp = cb + ch0;
    bf16x8 af;
    #pragma unroll
    for (int j=0;j<8;++j){
      float a = cbp[j] + w2[j]*bf2f((u16)x0[j])
                       + (w1[j]*m1)*bf2f((u16)x1[j])
                       + (w0[j]*m2)*bf2f((u16)x2[j]);
      af[j] = (short)f2bf(silu_f(a));
    }
    acc = __builtin_amdgcn_mfma_f32_16x16x32_bf16(af, bfrag[ks], acc, 0,0,0);
  }
  // C/D: col=lane&15 (proj idx), row=(lane>>4)*4+r (token offset)
  #pragma unroll
  for (int r=0;r<4;++r){
    int row = lq*4 + r;
    proj[(size_t)(tok0+row)*PSTR + lr] = acc[r];
  }
}

// ---------------- scan pass 1: per-chunk (P = prod dA, local h) ----------------
__global__ __launch_bounds__(384) void k_scan1(const float* __restrict__ proj, const u16* __restrict__ xB,
    const float* __restrict__ cw, const float* __restrict__ cb,
    const float* __restrict__ Wdt, const float* __restrict__ bdt, const float* __restrict__ Alog,
    float* __restrict__ Pg, float* __restrict__ Hg){
  __shared__ __align__(16) float ps[CHUNK*PSTR];
  int b = blockIdx.y, ch = blockIdx.x, d = threadIdx.x;
  int tok0 = b*LSEQ + ch*CHUNK;
  {
    const float4* src = (const float4*)(proj + (size_t)tok0*PSTR);
    float4* dst = (float4*)ps;
    for (int i = d; i < CHUNK*PSTR/4; i += 384) dst[i] = src[i];
  }
  __syncthreads();
  float wdt[12];
  #pragma unroll
  for (int r=0;r<12;++r) wdt[r] = Wdt[r*DIN+d];
  float bd = bdt[d];
  float Av = -__expf(Alog[d]);
  float c0=cw[d*3], c1=cw[d*3+1], c2=cw[d*3+2], cbv=cb[d];
  float xm1=0.f, xm2=0.f;
  if (ch > 0){
    xm1 = bf2f(xB[(size_t)(tok0-1)*DIN + d]);
    xm2 = bf2f(xB[(size_t)(tok0-2)*DIN + d]);
  }
  float h = 0.f, P = 1.f;
  #pragma unroll 4
  for (int il=0; il<CHUNK; ++il){
    float xc = bf2f(xB[(size_t)(tok0+il)*DIN + d]);
    const float4* pq = (const float4*)(ps + il*PSTR);
    float4 q0=pq[0], q1=pq[1], q2=pq[2], q3=pq[3];
    float a = cbv + c2*xc + c1*xm1 + c0*xm2;
    float uu = silu_f(a);
    float xv = bd + q0.x*wdt[0]+q0.y*wdt[1]+q0.z*wdt[2]+q0.w*wdt[3]
                  + q1.x*wdt[4]+q1.y*wdt[5]+q1.z*wdt[6]+q1.w*wdt[7]
                  + q2.x*wdt[8]+q2.y*wdt[9]+q2.z*wdt[10]+q2.w*wdt[11];
    float dt = softplus_f(xv);
    float dA = __expf(dt*Av);
    h = dA*h + dt*q3.x*uu;
    P *= dA;
    xm2 = xm1; xm1 = xc;
  }
  int o = (b*NCH + ch)*DIN + d;
  Pg[o] = P; Hg[o] = h;
}

// ---------------- scan pass 2: sequential carry combine over chunks ----------------
__global__ void k_scan2(const float* __restrict__ Pg, const float* __restrict__ Hg,
                        float* __restrict__ hin){
  int idx = blockIdx.x*256 + threadIdx.x;   // 0..6143 = b*384+d
  int b = idx/DIN, d = idx - b*DIN;
  float run = 0.f;
  #pragma unroll 4
  for (int ch=0; ch<NCH; ++ch){
    int o = (b*NCH+ch)*DIN + d;
    hin[o] = run;
    run = Pg[o]*run + Hg[o];
  }
}

// ---------------- scan pass 3: re-scan with carry, y in-place over zB ----------------
__global__ __launch_bounds__(384) void k_scan3(const float* __restrict__ proj, const u16* __restrict__ xB,
    const float* __restrict__ cw, const float* __restrict__ cb,
    const float* __restrict__ Wdt, const float* __restrict__ bdt,
    const float* __restrict__ Alog, const float* __restrict__ Dp,
    const float* __restrict__ hin, u16* __restrict__ zB){
  __shared__ __align__(16) float ps[CHUNK*PSTR];
  int b = blockIdx.y, ch = blockIdx.x, d = threadIdx.x;
  int tok0 = b*LSEQ + ch*CHUNK;
  {
    const float4* src = (const float4*)(proj + (size_t)tok0*PSTR);
    float4* dst = (float4*)ps;
    for (int i = d; i < CHUNK*PSTR/4; i += 384) dst[i] = src[i];
  }
  __syncthreads();
  float wdt[12];
  #pragma unroll
  for (int r=0;r<12;++r) wdt[r] = Wdt[r*DIN+d];
  float bd = bdt[d];
  float Av = -__expf(Alog[d]);
  float Dv = Dp[d];
  float c0=cw[d*3], c1=cw[d*3+1], c2=cw[d*3+2], cbv=cb[d];
  float xm1=0.f, xm2=0.f;
  if (ch > 0){
    xm1 = bf2f(xB[(size_t)(tok0-1)*DIN + d]);
    xm2 = bf2f(xB[(size_t)(tok0-2)*DIN + d]);
  }
  float h = hin[(b*NCH+ch)*DIN + d];
  #pragma unroll 4
  for (int il=0; il<CHUNK; ++il){
    float xc = bf2f(xB[(size_t)(tok0+il)*DIN + d]);
    const float4* pq = (const float4*)(ps + il*PSTR);
    float4 q0=pq[0], q1=pq[1], q2=pq[2], q3=pq[3];
    float a = cbv + c2*xc + c1*xm1 + c0*xm2;
    float uu = silu_f(a);
    float xv = bd + q0.x*wdt[0]+q0.y*wdt[1]+q0.z*wdt[2]+q0.w*wdt[3]
                  + q1.x*wdt[4]+q1.y*wdt[5]+q1.z*wdt[6]+q1.w*wdt[7]
                  + q2.x*wdt[8]+q2.y*wdt[9]+q2.z*wdt[10]+q2.w*wdt[11];
    float dt = softplus_f(xv);
    float dA = __expf(dt*Av);
    h = dA*h + dt*q3.x*uu;
    size_t zo = (size_t)(tok0+il)*DIN + d;
    float zz = bf2f(zB[zo]);
    zB[zo] = f2bf((h*q3.y + uu*Dv)*silu_f(zz));
    xm2 = xm1; xm1 = xc;
  }
}

// ---------------- GEMM2: out = y @ W_out + x ----------------
__global__ __launch_bounds__(256) void k_gemm2(const u16* __restrict__ A, const u16* __restrict__ B,
        const float* __restrict__ R, float* __restrict__ C)
{
  __shared__ __align__(16) u16 As[128*40];
  __shared__ __align__(16) u16 Bs[64*40];
  int tid = threadIdx.x;
  int m0 = blockIdx.x * 128;
  int n0 = blockIdx.y * 64;
  int wv = tid>>6, lane = tid&63;
  int lr = lane&15, lq = lane>>4;
  f32x4 acc[2][4];
  #pragma unroll
  for (int i=0;i<2;++i)
    #pragma unroll
    for (int j=0;j<4;++j) acc[i][j] = (f32x4){0.f,0.f,0.f,0.f};

  for (int k0=0; k0<DIN; k0+=32){
    #pragma unroll
    for (int it=0; it<2; ++it){
      int c = tid + 256*it;
      int row = c>>2, kc = (c&3)<<3;
      uint4 v = *(const uint4*)(A + (size_t)(m0+row)*DIN + k0 + kc);
      *(uint4*)(As + row*40 + kc) = v;
    }
    {
      int n = tid & 63, kb = (tid>>6)<<3;
      union { u16 s[8]; uint4 v; } tmp;
      #pragma unroll
      for (int j=0;j<8;++j) tmp.s[j] = B[(size_t)(k0+kb+j)*DIMC + n0 + n];
      *(uint4*)(Bs + n*40 + kb) = tmp.v;
    }
    __syncthreads();
    bf16x8 af[2], bfrag[4];
    af[0] = *(const bf16x8*)(As + (wv*32 +      lr)*40 + lq*8);
    af[1] = *(const bf16x8*)(As + (wv*32 + 16 + lr)*40 + lq*8);
    #pragma unroll
    for (int j=0;j<4;++j) bfrag[j] = *(const bf16x8*)(Bs + (j*16+lr)*40 + lq*8);
    #pragma unroll
    for (int i=0;i<2;++i)
      #pragma unroll
      for (int j=0;j<4;++j)
        acc[i][j] = __builtin_amdgcn_mfma_f32_16x16x32_bf16(af[i], bfrag[j], acc[i][j], 0,0,0);
    __syncthreads();
  }
  #pragma unroll
  for (int i=0;i<2;++i)
    #pragma unroll
    for (int j=0;j<4;++j)
      #pragma unroll
      for (int r=0;r<4;++r){
        int row = m0 + wv*32 + i*16 + lq*4 + r;
        int col = n0 + j*16 + lr;
        size_t o = (size_t)row*DIMC + col;
        C[o] = acc[i][j][r] + R[o];
      }
}

// ---------------- launch ----------------
extern "C" void kernel_launch(void* const* d_in, const int* in_sizes, int n_in,
                              void* d_out, int out_size, void* d_ws, size_t ws_size,
                              hipStream_t stream) {
  const float* x     = (const float*)d_in[0];
  const float* lnw   = (const float*)d_in[1];
  const float* lnb   = (const float*)d_in[2];
  const float* Win   = (const float*)d_in[3];
  const float* convw = (const float*)d_in[4];
  const float* convb = (const float*)d_in[5];
  const float* Wx    = (const float*)d_in[6];
  const float* Wdt   = (const float*)d_in[7];
  const float* bdt   = (const float*)d_in[8];
  const float* Alog  = (const float*)d_in[9];
  const float* Dp    = (const float*)d_in[10];
  const float* Wout  = (const float*)d_in[11];
  float* out = (float*)d_out;

  char* ws = (char*)d_ws;
  size_t off = 0;
  auto alloc = [&](size_t bytes){ size_t r = off; off += (bytes + 255) & ~(size_t)255; return r; };
  u16*   xB    = (u16*)  (ws + alloc((size_t)NTOK*DIN*2));
  u16*   zB    = (u16*)  (ws + alloc((size_t)NTOK*DIN*2));
  float* proj  = (float*)(ws + alloc((size_t)NTOK*PSTR*4));
  u16*   WinB  = (u16*)  (ws + alloc((size_t)DIMC*XZC*2));
  u16*   WoutB = (u16*)  (ws + alloc((size_t)DIN*DIMC*2));
  u16*   Wxp   = (u16*)  (ws + alloc((size_t)12*4*16*8*2));
  float* cwT   = (float*)(ws + alloc((size_t)3*DIN*4));
  float* Pg    = (float*)(ws + alloc((size_t)NBATCH*NCH*DIN*4));
  float* Hg    = (float*)(ws + alloc((size_t)NBATCH*NCH*DIN*4));
  float* hin   = (float*)(ws + alloc((size_t)NBATCH*NCH*DIN*4));
  // total ≈ 231 MB

  k_convert<<<576, 256, 0, stream>>>(Win, Wout, Wx, convw, WinB, WoutB, Wxp, cwT);
  k_lngemm1<<<NTOK/128, 256, 0, stream>>>(x, lnw, lnb, WinB, xB, zB);
  k_conv<<<NTOK/64, 256, 0, stream>>>(xB, cwT, convb, Wxp, proj);
  {
    dim3 g(NCH, NBATCH);
    k_scan1<<<g, 384, 0, stream>>>(proj, xB, convw, convb, Wdt, bdt, Alog, Pg, Hg);
  }
  k_scan2<<<24, 256, 0, stream>>>(Pg, Hg, hin);
  {
    dim3 g(NCH, NBATCH);
    k_scan3<<<g, 384, 0, stream>>>(proj, xB, convw, convb, Wdt, bdt, Alog, Dp, hin, zB);
  }
  {
    dim3 g(NTOK/128, DIMC/64);
    k_gemm2<<<g, 256, 0, stream>>>(zB, WoutB, x, out);
  }
}

// Round 5
// 768.765 us; speedup vs baseline: 2.3270x; 1.0779x over previous
//
#include <hip/hip_runtime.h>
#include <math.h>

#define DIMC 192
#define DIN 384
#define XZC 768
#define NPROJ 14
#define PSTR 16
#define LSEQ 9216
#define NBATCH 16
#define NTOK (NBATCH*LSEQ)     // 147456
#define CHUNK 128
#define NCH (LSEQ/CHUNK)       // 72

typedef unsigned short u16;
typedef unsigned int u32;
typedef __attribute__((ext_vector_type(8))) short bf16x8;
typedef __attribute__((ext_vector_type(4))) float f32x4;

__device__ __forceinline__ float bf2f(u16 a){
  union { u32 u; float f; } v; v.u = ((u32)a)<<16; return v.f;
}
__device__ __forceinline__ u16 f2bf(float f){
  union { u32 u; float f; } v; v.f = f;
  u32 r = v.u + 0x7FFFu + ((v.u>>16)&1u);
  return (u16)(r>>16);
}
__device__ __forceinline__ float frcp(float x){ return __builtin_amdgcn_rcpf(x); }
__device__ __forceinline__ float softplus_f(float x){
  return fmaxf(x, 0.f) + __logf(1.f + __expf(-fabsf(x)));
}
__device__ __forceinline__ float silu_f(float a){
  return a * frcp(1.f + __expf(-a));
}

// ---------------- weight packing ----------------
// Bp1: W_in (192x768) packed in B-fragment order for 16x16x32 MFMA:
//   Bp1[((nt*6+ks)*64+lane)*8+j] = Win[(ks*32+(lane>>4)*8+j)*XZC + nt*16+(lane&15)]
// Bp2: W_out (384x192) likewise with 12 ksteps.
// Wxp: Wx in B-frag order (N=16 pad). cwT[tap][384]: transposed conv weights.
__global__ void k_convert(const float* __restrict__ Win, const float* __restrict__ Wout,
                          const float* __restrict__ Wx, const float* __restrict__ cw,
                          u16* __restrict__ Bp1, u16* __restrict__ Bp2,
                          u16* __restrict__ Wxp, float* __restrict__ cwT){
  int i = blockIdx.x*256 + threadIdx.x;
  if (i < XZC*DIMC){          // 147456
    int j = i&7, lane = (i>>3)&63, rest = i>>9;
    int ks = rest%6, nt = rest/6;
    int k = ks*32 + (lane>>4)*8 + j, n = nt*16 + (lane&15);
    Bp1[i] = f2bf(Win[(size_t)k*XZC + n]);
  }
  if (i < DIN*DIMC){          // 73728
    int j = i&7, lane = (i>>3)&63, rest = i>>9;
    int ks = rest%12, nt = rest/12;
    int k = ks*32 + (lane>>4)*8 + j, n = nt*16 + (lane&15);
    Bp2[i] = f2bf(Wout[(size_t)k*DIMC + n]);
  }
  if (i < 12*4*16*8){
    int j = i&7, n = (i>>3)&15, quad = (i>>7)&3, kstep = i>>9;
    int k = kstep*32 + quad*8 + j;
    Wxp[i] = (n < NPROJ) ? f2bf(Wx[k*NPROJ + n]) : (u16)0;
  }
  if (i < 3*DIN){
    int tap = i / DIN, ch = i - tap*DIN;
    cwT[i] = cw[ch*3 + tap];
  }
}

// ---------------- fused LayerNorm + GEMM1 (register-direct MFMA, no LDS) ----------------
// wave = 16 tokens. Lane (lr=token, lq=kquad) loads its 48 LN channels,
// quad-reduces stats via shfl_xor(16/32), builds 6 A-frags, loops 48 n-tiles.
__global__ __launch_bounds__(256) void k_lngemm1(const float* __restrict__ x,
        const float* __restrict__ lnw, const float* __restrict__ lnb,
        const u16* __restrict__ Bp1, u16* __restrict__ xB, u16* __restrict__ zB)
{
  int tid = threadIdx.x, wv = tid>>6, lane = tid&63;
  int lr = lane&15, lq = lane>>4;
  int tokw = blockIdx.x*64 + wv*16;
  int token = tokw + lr;
  const float* xp = x + (size_t)token*DIMC + lq*8;
  float v[48];
  #pragma unroll
  for (int ks=0;ks<6;++ks){
    float4 a = *(const float4*)(xp + ks*32);
    float4 b = *(const float4*)(xp + ks*32 + 4);
    v[ks*8+0]=a.x; v[ks*8+1]=a.y; v[ks*8+2]=a.z; v[ks*8+3]=a.w;
    v[ks*8+4]=b.x; v[ks*8+5]=b.y; v[ks*8+6]=b.z; v[ks*8+7]=b.w;
  }
  float s = 0.f;
  #pragma unroll
  for (int j=0;j<48;++j) s += v[j];
  s += __shfl_xor(s, 16); s += __shfl_xor(s, 32);
  float mu = s * (1.0f/DIMC);
  float q = 0.f;
  #pragma unroll
  for (int j=0;j<48;++j){ float d = v[j]-mu; q += d*d; }
  q += __shfl_xor(q, 16); q += __shfl_xor(q, 32);
  float rstd = rsqrtf(q*(1.0f/DIMC) + 1e-5f);
  bf16x8 af[6];
  #pragma unroll
  for (int ks=0;ks<6;++ks){
    const float* wp = lnw + lq*8 + ks*32;
    const float* bp = lnb + lq*8 + ks*32;
    float4 w0 = *(const float4*)(wp),   w1 = *(const float4*)(wp+4);
    float4 b0 = *(const float4*)(bp),   b1 = *(const float4*)(bp+4);
    float wj[8] = {w0.x,w0.y,w0.z,w0.w,w1.x,w1.y,w1.z,w1.w};
    float bj[8] = {b0.x,b0.y,b0.z,b0.w,b1.x,b1.y,b1.z,b1.w};
    #pragma unroll
    for (int j=0;j<8;++j)
      af[ks][j] = (short)f2bf((v[ks*8+j]-mu)*rstd*wj[j] + bj[j]);
  }
  #pragma unroll 2
  for (int nt=0; nt<48; ++nt){
    f32x4 acc = (f32x4){0.f,0.f,0.f,0.f};
    #pragma unroll
    for (int ks=0;ks<6;++ks){
      bf16x8 bf_ = *(const bf16x8*)(Bp1 + (size_t)((nt*6+ks)<<9) + (size_t)lane*8);
      acc = __builtin_amdgcn_mfma_f32_16x16x32_bf16(af[ks], bf_, acc, 0,0,0);
    }
    int col = nt*16 + lr;
    #pragma unroll
    for (int r=0;r<4;++r){
      int row = tokw + lq*4 + r;
      u16 val = f2bf(acc[r]);
      if (col < DIN) xB[(size_t)row*DIN + col] = val;
      else           zB[(size_t)row*DIN + (col-DIN)] = val;
    }
  }
}

// ---------------- conv3 + SiLU + MFMA projection ----------------
__global__ __launch_bounds__(256) void k_conv(const u16* __restrict__ xB,
        const float* __restrict__ cwT, const float* __restrict__ cb,
        const u16* __restrict__ Wxp, float* __restrict__ proj){
  int tid = threadIdx.x, wv = tid>>6, lane = tid&63;
  int lr = lane&15, lq = lane>>4;
  int tok0 = blockIdx.x*64 + wv*16;
  int token = tok0 + lr;
  int l = token % LSEQ;
  float m1 = (l>=1)?1.f:0.f, m2 = (l>=2)?1.f:0.f;
  int tm1 = (l>=1)? token-1 : token;
  int tm2 = (l>=2)? token-2 : token;
  bf16x8 bfrag[12];
  #pragma unroll
  for (int ks=0;ks<12;++ks)
    bfrag[ks] = *(const bf16x8*)(Wxp + (size_t)ks*512 + (size_t)lane*8);
  f32x4 acc = (f32x4){0.f,0.f,0.f,0.f};
  #pragma unroll
  for (int ks=0;ks<12;++ks){
    int ch0 = ks*32 + lq*8;
    bf16x8 x0 = *(const bf16x8*)(xB + (size_t)token*DIN + ch0);
    bf16x8 x1 = *(const bf16x8*)(xB + (size_t)tm1*DIN + ch0);
    bf16x8 x2 = *(const bf16x8*)(xB + (size_t)tm2*DIN + ch0);
    const float* w2 = cwT + 2*DIN + ch0;
    const float* w1 = cwT + 1*DIN + ch0;
    const float* w0 = cwT + 0*DIN + ch0;
    const float* cbp = cb + ch0;
    bf16x8 af;
    #pragma unroll
    for (int j=0;j<8;++j){
      float a = cbp[j] + w2[j]*bf2f((u16)x0[j])
                       + (w1[j]*m1)*bf2f((u16)x1[j])
                       + (w0[j]*m2)*bf2f((u16)x2[j]);
      af[j] = (short)f2bf(silu_f(a));
    }
    acc = __builtin_amdgcn_mfma_f32_16x16x32_bf16(af, bfrag[ks], acc, 0,0,0);
  }
  #pragma unroll
  for (int r=0;r<4;++r){
    int row = lq*4 + r;
    proj[(size_t)(tok0+row)*PSTR + lr] = acc[r];
  }
}

// ---------------- scan pass 1 ----------------
__global__ __launch_bounds__(384) void k_scan1(const float* __restrict__ proj, const u16* __restrict__ xB,
    const float* __restrict__ cw, const float* __restrict__ cb,
    const float* __restrict__ Wdt, const float* __restrict__ bdt, const float* __restrict__ Alog,
    float* __restrict__ Pg, float* __restrict__ Hg){
  __shared__ __align__(16) float ps[CHUNK*PSTR];
  int b = blockIdx.y, ch = blockIdx.x, d = threadIdx.x;
  int tok0 = b*LSEQ + ch*CHUNK;
  {
    const float4* src = (const float4*)(proj + (size_t)tok0*PSTR);
    float4* dst = (float4*)ps;
    for (int i = d; i < CHUNK*PSTR/4; i += 384) dst[i] = src[i];
  }
  __syncthreads();
  float wdt[12];
  #pragma unroll
  for (int r=0;r<12;++r) wdt[r] = Wdt[r*DIN+d];
  float bd = bdt[d];
  float Av = -__expf(Alog[d]);
  float c0=cw[d*3], c1=cw[d*3+1], c2=cw[d*3+2], cbv=cb[d];
  float xm1=0.f, xm2=0.f;
  if (ch > 0){
    xm1 = bf2f(xB[(size_t)(tok0-1)*DIN + d]);
    xm2 = bf2f(xB[(size_t)(tok0-2)*DIN + d]);
  }
  float h = 0.f, P = 1.f;
  #pragma unroll 4
  for (int il=0; il<CHUNK; ++il){
    float xc = bf2f(xB[(size_t)(tok0+il)*DIN + d]);
    const float4* pq = (const float4*)(ps + il*PSTR);
    float4 q0=pq[0], q1=pq[1], q2=pq[2], q3=pq[3];
    float a = cbv + c2*xc + c1*xm1 + c0*xm2;
    float uu = silu_f(a);
    float xv = bd + q0.x*wdt[0]+q0.y*wdt[1]+q0.z*wdt[2]+q0.w*wdt[3]
                  + q1.x*wdt[4]+q1.y*wdt[5]+q1.z*wdt[6]+q1.w*wdt[7]
                  + q2.x*wdt[8]+q2.y*wdt[9]+q2.z*wdt[10]+q2.w*wdt[11];
    float dt = softplus_f(xv);
    float dA = __expf(dt*Av);
    h = dA*h + dt*q3.x*uu;
    P *= dA;
    xm2 = xm1; xm1 = xc;
  }
  int o = (b*NCH + ch)*DIN + d;
  Pg[o] = P; Hg[o] = h;
}

// ---------------- scan pass 2 ----------------
__global__ void k_scan2(const float* __restrict__ Pg, const float* __restrict__ Hg,
                        float* __restrict__ hin){
  int idx = blockIdx.x*256 + threadIdx.x;
  int b = idx/DIN, d = idx - b*DIN;
  float run = 0.f;
  #pragma unroll 4
  for (int ch=0; ch<NCH; ++ch){
    int o = (b*NCH+ch)*DIN + d;
    hin[o] = run;
    run = Pg[o]*run + Hg[o];
  }
}

// ---------------- scan pass 3 ----------------
__global__ __launch_bounds__(384) void k_scan3(const float* __restrict__ proj, const u16* __restrict__ xB,
    const float* __restrict__ cw, const float* __restrict__ cb,
    const float* __restrict__ Wdt, const float* __restrict__ bdt,
    const float* __restrict__ Alog, const float* __restrict__ Dp,
    const float* __restrict__ hin, u16* __restrict__ zB){
  __shared__ __align__(16) float ps[CHUNK*PSTR];
  int b = blockIdx.y, ch = blockIdx.x, d = threadIdx.x;
  int tok0 = b*LSEQ + ch*CHUNK;
  {
    const float4* src = (const float4*)(proj + (size_t)tok0*PSTR);
    float4* dst = (float4*)ps;
    for (int i = d; i < CHUNK*PSTR/4; i += 384) dst[i] = src[i];
  }
  __syncthreads();
  float wdt[12];
  #pragma unroll
  for (int r=0;r<12;++r) wdt[r] = Wdt[r*DIN+d];
  float bd = bdt[d];
  float Av = -__expf(Alog[d]);
  float Dv = Dp[d];
  float c0=cw[d*3], c1=cw[d*3+1], c2=cw[d*3+2], cbv=cb[d];
  float xm1=0.f, xm2=0.f;
  if (ch > 0){
    xm1 = bf2f(xB[(size_t)(tok0-1)*DIN + d]);
    xm2 = bf2f(xB[(size_t)(tok0-2)*DIN + d]);
  }
  float h = hin[(b*NCH+ch)*DIN + d];
  #pragma unroll 4
  for (int il=0; il<CHUNK; ++il){
    float xc = bf2f(xB[(size_t)(tok0+il)*DIN + d]);
    const float4* pq = (const float4*)(ps + il*PSTR);
    float4 q0=pq[0], q1=pq[1], q2=pq[2], q3=pq[3];
    float a = cbv + c2*xc + c1*xm1 + c0*xm2;
    float uu = silu_f(a);
    float xv = bd + q0.x*wdt[0]+q0.y*wdt[1]+q0.z*wdt[2]+q0.w*wdt[3]
                  + q1.x*wdt[4]+q1.y*wdt[5]+q1.z*wdt[6]+q1.w*wdt[7]
                  + q2.x*wdt[8]+q2.y*wdt[9]+q2.z*wdt[10]+q2.w*wdt[11];
    float dt = softplus_f(xv);
    float dA = __expf(dt*Av);
    h = dA*h + dt*q3.x*uu;
    size_t zo = (size_t)(tok0+il)*DIN + d;
    float zz = bf2f(zB[zo]);
    zB[zo] = f2bf((h*q3.y + uu*Dv)*silu_f(zz));
    xm2 = xm1; xm1 = xc;
  }
}

// ---------------- GEMM2 (register-direct MFMA): out = y @ W_out + x ----------------
__global__ __launch_bounds__(256) void k_gemm2(const u16* __restrict__ A, const u16* __restrict__ Bp2,
        const float* __restrict__ R, float* __restrict__ C)
{
  int tid = threadIdx.x, wv = tid>>6, lane = tid&63;
  int lr = lane&15, lq = lane>>4;
  int tokw = blockIdx.x*64 + wv*16;
  int token = tokw + lr;
  bf16x8 af[12];
  #pragma unroll
  for (int ks=0;ks<12;++ks)
    af[ks] = *(const bf16x8*)(A + (size_t)token*DIN + ks*32 + lq*8);
  #pragma unroll 2
  for (int nt=0; nt<12; ++nt){
    f32x4 acc = (f32x4){0.f,0.f,0.f,0.f};
    #pragma unroll
    for (int ks=0;ks<12;++ks){
      bf16x8 bf_ = *(const bf16x8*)(Bp2 + (size_t)((nt*12+ks)<<9) + (size_t)lane*8);
      acc = __builtin_amdgcn_mfma_f32_16x16x32_bf16(af[ks], bf_, acc, 0,0,0);
    }
    int col = nt*16 + lr;
    #pragma unroll
    for (int r=0;r<4;++r){
      int row = tokw + lq*4 + r;
      size_t o = (size_t)row*DIMC + col;
      C[o] = acc[r] + R[o];
    }
  }
}

// ---------------- launch ----------------
extern "C" void kernel_launch(void* const* d_in, const int* in_sizes, int n_in,
                              void* d_out, int out_size, void* d_ws, size_t ws_size,
                              hipStream_t stream) {
  const float* x     = (const float*)d_in[0];
  const float* lnw   = (const float*)d_in[1];
  const float* lnb   = (const float*)d_in[2];
  const float* Win   = (const float*)d_in[3];
  const float* convw = (const float*)d_in[4];
  const float* convb = (const float*)d_in[5];
  const float* Wx    = (const float*)d_in[6];
  const float* Wdt   = (const float*)d_in[7];
  const float* bdt   = (const float*)d_in[8];
  const float* Alog  = (const float*)d_in[9];
  const float* Dp    = (const float*)d_in[10];
  const float* Wout  = (const float*)d_in[11];
  float* out = (float*)d_out;

  char* ws = (char*)d_ws;
  size_t off = 0;
  auto alloc = [&](size_t bytes){ size_t r = off; off += (bytes + 255) & ~(size_t)255; return r; };
  u16*   xB    = (u16*)  (ws + alloc((size_t)NTOK*DIN*2));
  u16*   zB    = (u16*)  (ws + alloc((size_t)NTOK*DIN*2));
  float* proj  = (float*)(ws + alloc((size_t)NTOK*PSTR*4));
  u16*   Bp1   = (u16*)  (ws + alloc((size_t)XZC*DIMC*2));
  u16*   Bp2   = (u16*)  (ws + alloc((size_t)DIN*DIMC*2));
  u16*   Wxp   = (u16*)  (ws + alloc((size_t)12*4*16*8*2));
  float* cwT   = (float*)(ws + alloc((size_t)3*DIN*4));
  float* Pg    = (float*)(ws + alloc((size_t)NBATCH*NCH*DIN*4));
  float* Hg    = (float*)(ws + alloc((size_t)NBATCH*NCH*DIN*4));
  float* hin   = (float*)(ws + alloc((size_t)NBATCH*NCH*DIN*4));

  k_convert<<<576, 256, 0, stream>>>(Win, Wout, Wx, convw, Bp1, Bp2, Wxp, cwT);
  k_lngemm1<<<NTOK/64, 256, 0, stream>>>(x, lnw, lnb, Bp1, xB, zB);
  k_conv<<<NTOK/64, 256, 0, stream>>>(xB, cwT, convb, Wxp, proj);
  {
    dim3 g(NCH, NBATCH);
    k_scan1<<<g, 384, 0, stream>>>(proj, xB, convw, convb, Wdt, bdt, Alog, Pg, Hg);
  }
  k_scan2<<<24, 256, 0, stream>>>(Pg, Hg, hin);
  {
    dim3 g(NCH, NBATCH);
    k_scan3<<<g, 384, 0, stream>>>(proj, xB, convw, convb, Wdt, bdt, Alog, Dp, hin, zB);
  }
  {
    dim3 g(NTOK/64, DIMC/64);
    dim3 g2(NTOK/64);
    k_gemm2<<<g2, 256, 0, stream>>>(zB, Bp2, x, out);
  }
}